// Round 7
// baseline (246.604 us; speedup 1.0000x reference)
//
#include <hip/hip_runtime.h>

typedef unsigned short u16;
typedef unsigned int u32;
typedef __bf16 bf16x8 __attribute__((ext_vector_type(8)));
typedef u16 u16x8 __attribute__((ext_vector_type(8)));
typedef u16 u16x4 __attribute__((ext_vector_type(4)));
typedef float f32x4 __attribute__((ext_vector_type(4)));
typedef float f32x16 __attribute__((ext_vector_type(16)));

#define BHTD 8388608  // 4*16*2048*64 elements per Q/K/V tensor
#define QSCALE 0.18033688f  // 0.125 * log2(e): softmax in exp2 domain

__device__ __forceinline__ u16 f2bf(float f) {
  union { float f; u32 u; } x; x.f = f;
  u32 r = (x.u + 0x7FFFu + ((x.u >> 16) & 1u)) >> 16;
  return (u16)r;
}

__device__ __forceinline__ u32 cvt_pk_bf16(float lo, float hi) {
  u32 r;
  asm("v_cvt_pk_bf16_f32 %0, %1, %2" : "=v"(r) : "v"(lo), "v"(hi));
  return r;
}

// v_permlane32_swap_b32: x.hi32lanes <-> y.lo32lanes (both updated in place).
// NOTE: only used with DISTINCT source values (P^T exchange, proven r5). The
// identical-operand reduction variant (r6 xhalf_*) produced NaNs on HW.
__device__ __forceinline__ void permlane32_swap(u32& x, u32& y) {
  asm("v_permlane32_swap_b32 %0, %1" : "+v"(x), "+v"(y));
}

__device__ __forceinline__ void async_copy16(const u16* gsrc, u16* ldst) {
  __builtin_amdgcn_global_load_lds(
      (const __attribute__((address_space(1))) void*)gsrc,
      (__attribute__((address_space(3))) void*)ldst, 16, 0, 0);
}

// ---------------- fp32 -> bf16 elementwise convert ----------------
__global__ __launch_bounds__(256) void conv_x_kernel(const float4* __restrict__ in,
                                                     u16x4* __restrict__ out, int n4) {
  int i = blockIdx.x * 256 + threadIdx.x;
  int stride = gridDim.x * 256;
  for (; i < n4; i += stride) {
    float4 v = in[i];
    u16x4 o = { f2bf(v.x), f2bf(v.y), f2bf(v.z), f2bf(v.w) };
    out[i] = o;
  }
}

// ---------------- fp32 [K][N] -> bf16 transposed [N][K] ----------------
__global__ __launch_bounds__(256) void transpose_bf16(const float* __restrict__ W,
                                                      u16* __restrict__ Wt, int K, int N) {
  __shared__ float t[64][65];
  int c0 = blockIdx.x * 64;  // col block (N)
  int r0 = blockIdx.y * 64;  // row block (K)
  int c = threadIdx.x & 63;
  int r4 = threadIdx.x >> 6;
#pragma unroll
  for (int j = 0; j < 16; ++j) {
    int r = j * 4 + r4;
    t[r][c] = W[(size_t)(r0 + r) * N + (c0 + c)];
  }
  __syncthreads();
#pragma unroll
  for (int j = 0; j < 16; ++j) {
    int n = j * 4 + r4;
    Wt[(size_t)(c0 + n) * K + (r0 + c)] = f2bf(t[c][n]);
  }
}

// ---------------- bf16 GEMM: C[M][N] = A[M][1024] * Bt[N][1024]^T + bias ----------------
// 128x128 tile, 4 waves (2x2), BK=64, global_load_lds staging with XOR slot swizzle.
// MODE 0: scatter to QKV; Q (pre-scaled by QSCALE),K as [B][H][T][64], V TRANSPOSED
// as [B][H][64][T] (bf16).  MODE 1: fp32 out [M][1024].
template <int MODE>
__global__ __launch_bounds__(256) void gemm_bf16(const u16* __restrict__ A,
                                                 const u16* __restrict__ Bt,
                                                 const float* __restrict__ bias,
                                                 float* __restrict__ outp,
                                                 u16* __restrict__ qkv, int grid_n) {
  __shared__ __attribute__((aligned(16))) u16 A_lds[128 * 64];
  __shared__ __attribute__((aligned(16))) u16 B_lds[128 * 64];
  const int tid = threadIdx.x;
  const int lane = tid & 63, wave = tid >> 6;
  const int wr = wave >> 1, wc = wave & 1;
  const int bn = blockIdx.x % grid_n, bm = blockIdx.x / grid_n;
  const int m0 = bm * 128, n0 = bn * 128;
  const int g = lane >> 4, c16 = lane & 15;
  const int lrow = lane >> 3, lslot = lane & 7;

  f32x4 acc[4][4] = {};

  for (int kt = 0; kt < 16; ++kt) {
#pragma unroll
    for (int i = 0; i < 4; ++i) {
      int mloc = (wave * 4 + i) * 8 + lrow;
      int col = kt * 64 + ((lslot ^ (mloc & 7)) << 3);  // pre-swizzled global source
      async_copy16(&A[(size_t)(m0 + mloc) * 1024 + col], &A_lds[(wave * 4 + i) * 512]);
      async_copy16(&Bt[(size_t)(n0 + mloc) * 1024 + col], &B_lds[(wave * 4 + i) * 512]);
    }
    __syncthreads();  // compiler drains vmcnt before barrier
#pragma unroll
    for (int kk = 0; kk < 2; ++kk) {
      bf16x8 af[4], bfr[4];
#pragma unroll
      for (int mb = 0; mb < 4; ++mb) {
        int row = wr * 64 + mb * 16 + c16;
        int slot = (kk * 4 + g) ^ (row & 7);
        af[mb] = *(const bf16x8*)&A_lds[row * 64 + slot * 8];
        int rowb = wc * 64 + mb * 16 + c16;
        int slotb = (kk * 4 + g) ^ (rowb & 7);
        bfr[mb] = *(const bf16x8*)&B_lds[rowb * 64 + slotb * 8];
      }
#pragma unroll
      for (int mb = 0; mb < 4; ++mb)
#pragma unroll
        for (int nb = 0; nb < 4; ++nb)
          acc[mb][nb] = __builtin_amdgcn_mfma_f32_16x16x32_bf16(af[mb], bfr[nb], acc[mb][nb], 0, 0, 0);
    }
    __syncthreads();
  }

  float bv[4];
#pragma unroll
  for (int nb = 0; nb < 4; ++nb) bv[nb] = bias[n0 + wc * 64 + nb * 16 + c16];

#pragma unroll
  for (int mb = 0; mb < 4; ++mb) {
    int row0 = m0 + wr * 64 + mb * 16 + g * 4;
#pragma unroll
    for (int nb = 0; nb < 4; ++nb) {
      int col = n0 + wc * 64 + nb * 16 + c16;
      float bvn = bv[nb];
      if (MODE == 0) {
        int sel = col >> 10, ci = col & 1023;
        int hh = ci >> 6, d = ci & 63;
        int bb = row0 >> 11, t0 = row0 & 2047;
        float qs = (sel == 0) ? QSCALE : 1.0f;
        if (sel == 2) {
          // V transposed: [bh][d][t], 4 consecutive t -> one 8B store
          u16x4 pk;
#pragma unroll
          for (int r = 0; r < 4; ++r) pk[r] = f2bf(acc[mb][nb][r] + bvn);
          *(u16x4*)&qkv[(size_t)2 * BHTD + (((size_t)(bb * 16 + hh) * 64 + d) << 11) + t0] = pk;
        } else {
#pragma unroll
          for (int r = 0; r < 4; ++r) {
            qkv[(size_t)sel * BHTD + (((size_t)(bb * 16 + hh) * 2048 + t0 + r) << 6) + d] =
                f2bf((acc[mb][nb][r] + bvn) * qs);
          }
        }
      } else {
#pragma unroll
        for (int r = 0; r < 4; ++r)
          outp[((size_t)(row0 + r) << 10) + col] = acc[mb][nb][r] + bvn;
      }
    }
  }
}

// ---------------- causal flash attention: folded pairs, K in LDS, V direct ----------------
// 1 block = (pj, hd), 128 threads (2 waves x 32 q rows). Causal fold: block runs TWO
// sequential flash passes over 64-row q-tiles {31-pj, pj} -> every block does exactly
// 33 compute tiles per wave -> uniform grid, occupancy flat. K double-buffered in
// 16KB LDS (8 blocks/CU); V direct from global (L2-resident), depth-2 pipelined.
// Cross-half reductions via __shfl_xor (r6's identical-operand permlane reduce NaN'd).
// Finite -1e30 masking: no inf arithmetic anywhere.
__global__ __launch_bounds__(128, 4) void attn_fwd(const u16* __restrict__ Q,
                                                   const u16* __restrict__ K,
                                                   const u16* __restrict__ VT,
                                                   u16* __restrict__ Y) {
  __shared__ __attribute__((aligned(16))) u16 Kl[2][64 * 64];
  const float NEG_BIG = -1e30f;

  int bid = blockIdx.x;
  int pj = bid >> 6, hd = bid & 63;  // hd&7 spreads XCDs -> 8 heads/XCD (K+V ~4MB = L2)
  size_t hb = (size_t)hd * (2048 * 64);
  const u16* Qh = Q + hb;
  const u16* Kh = K + hb;
  const u16* Vh = VT + hb;  // [64][2048]
  int tid = threadIdx.x, lane = tid & 63, w = tid >> 6;
  int c32 = lane & 31, h = lane >> 5;
  const int xs = c32 & 7;  // read-side row-xor for swizzle

  // staging chunk geometry: 512 x 16B chunks per tile, 4 per thread;
  // global col pre-swizzled so linear LDS dest + XOR read works (rule #21)
  int ch[4], sr[4], sw[4];
#pragma unroll
  for (int i = 0; i < 4; ++i) {
    ch[i] = tid + 128 * i;
    sr[i] = ch[i] >> 3;
    sw[i] = ((ch[i] & 7) ^ (sr[i] & 7)) << 3;
  }

  for (int pass = 0; pass < 2; ++pass) {
    const int t64 = pass ? pj : 31 - pj;  // heavy pass first
    const int nt = t64 + 1;
    const int qw0 = t64 * 64 + w * 32;
    const int qrow = qw0 + c32;

    bf16x8 qf[4];  // Q[qrow][dk*16 + 8h .. +7], pre-scaled by QSCALE
#pragma unroll
    for (int dk = 0; dk < 4; ++dk)
      qf[dk] = *(const bf16x8*)&Qh[(size_t)qrow * 64 + dk * 16 + 8 * h];

    // prologue: stage K tile 0 into buf 0
#pragma unroll
    for (int i = 0; i < 4; ++i)
      async_copy16(&Kh[(size_t)sr[i] * 64 + sw[i]], &Kl[0][ch[i] << 3]);

    float m = NEG_BIG, l = 0.f;
    f32x16 o0 = {}, o1 = {};  // O^T[d][q=c32]

    for (int it = 0; it < nt; ++it) {
      int kv0 = it << 6;
      int cb = it & 1;
      __syncthreads();  // vmcnt drained first -> Kl[cb] staged for both waves

      if (it + 1 < nt) {  // stage next K tile; hidden under this tile's compute
        int kv1 = kv0 + 64;
#pragma unroll
        for (int i = 0; i < 4; ++i)
          async_copy16(&Kh[(size_t)(kv1 + sr[i]) * 64 + sw[i]], &Kl[cb ^ 1][ch[i] << 3]);
      }

      // ---- kf from LDS; S^T = K * Q^T ----
      bf16x8 kf[2][4];
#pragma unroll
      for (int kb = 0; kb < 2; ++kb)
#pragma unroll
        for (int dk = 0; dk < 4; ++dk)
          kf[kb][dk] =
              *(const bf16x8*)&Kl[cb][(kb * 32 + c32) * 64 + (((2 * dk + h) ^ xs) << 3)];
      f32x16 s0 = {}, s1 = {};
      __builtin_amdgcn_s_setprio(1);
#pragma unroll
      for (int dk = 0; dk < 4; ++dk) {
        s0 = __builtin_amdgcn_mfma_f32_32x32x16_bf16(kf[0][dk], qf[dk], s0, 0, 0, 0);
        s1 = __builtin_amdgcn_mfma_f32_32x32x16_bf16(kf[1][dk], qf[dk], s1, 0, 0, 0);
      }
      __builtin_amdgcn_s_setprio(0);

      // causal mask: only the diagonal (= last) tile; finite mask value
      if (it + 1 == nt) {
        int kvb = kv0 + 4 * h;
#pragma unroll
        for (int reg = 0; reg < 16; ++reg) {
          int kvl = kvb + 8 * (reg >> 2) + (reg & 3);  // kv of s0[reg]
          if (kvl > qrow) s0[reg] = NEG_BIG;
          if (kvl + 32 > qrow) s1[reg] = NEG_BIG;
        }
      }

      // ---- online softmax: per-lane row, ILP tree + shfl_xor cross-half ----
      float a0 = fmaxf(s0[0], s1[0]), a1 = fmaxf(s0[1], s1[1]);
      float a2 = fmaxf(s0[2], s1[2]), a3 = fmaxf(s0[3], s1[3]);
#pragma unroll
      for (int i = 4; i < 16; i += 4) {
        a0 = fmaxf(a0, fmaxf(s0[i], s1[i]));
        a1 = fmaxf(a1, fmaxf(s0[i + 1], s1[i + 1]));
        a2 = fmaxf(a2, fmaxf(s0[i + 2], s1[i + 2]));
        a3 = fmaxf(a3, fmaxf(s0[i + 3], s1[i + 3]));
      }
      float rm = fmaxf(fmaxf(a0, a1), fmaxf(a2, a3));
      rm = fmaxf(rm, __shfl_xor(rm, 32));
      if (__any(rm - m > 8.f)) {  // defer-max: rescale only when a row grew >2^8
        float mn = fmaxf(m, rm);
        float alpha = __builtin_exp2f(m - mn);
        l *= alpha;
        o0 *= alpha;
        o1 *= alpha;
        m = mn;
      }
#pragma unroll
      for (int i = 0; i < 16; ++i) s0[i] = __builtin_exp2f(s0[i] - m);
#pragma unroll
      for (int i = 0; i < 16; ++i) s1[i] = __builtin_exp2f(s1[i] - m);
      float b0 = s0[0] + s1[0], b1 = s0[1] + s1[1];
      float b2 = s0[2] + s1[2], b3 = s0[3] + s1[3];
#pragma unroll
      for (int i = 4; i < 16; i += 4) {
        b0 += s0[i] + s1[i];
        b1 += s0[i + 1] + s1[i + 1];
        b2 += s0[i + 2] + s1[i + 2];
        b3 += s0[i + 3] + s1[i + 3];
      }
      float rs = (b0 + b1) + (b2 + b3);
      rs += __shfl_xor(rs, 32);
      l += rs;

      // ---- P^T: pack pairs to bf16, half-exchange via permlane32_swap ----
      u32 pw0[8], pw1[8];
#pragma unroll
      for (int mm = 0; mm < 8; ++mm) {
        pw0[mm] = cvt_pk_bf16(s0[2 * mm], s0[2 * mm + 1]);
        pw1[mm] = cvt_pk_bf16(s1[2 * mm], s1[2 * mm + 1]);
      }
      permlane32_swap(pw0[0], pw0[2]); permlane32_swap(pw0[1], pw0[3]);
      permlane32_swap(pw0[4], pw0[6]); permlane32_swap(pw0[5], pw0[7]);
      permlane32_swap(pw1[0], pw1[2]); permlane32_swap(pw1[1], pw1[3]);
      permlane32_swap(pw1[4], pw1[6]); permlane32_swap(pw1[5], pw1[7]);

      // ---- O^T += V^T * P^T; V direct from global, depth-2 pipelined ----
      bf16x8 va[2], vb[2];
#pragma unroll
      for (int c = 0; c < 2; ++c) {
        va[c] = *(const bf16x8*)&Vh[(size_t)c32 * 2048 + kv0 + c * 16 + 8 * h];
        vb[c] = *(const bf16x8*)&Vh[(size_t)(32 + c32) * 2048 + kv0 + c * 16 + 8 * h];
      }
      __builtin_amdgcn_s_setprio(1);
#pragma unroll
      for (int c = 0; c < 4; ++c) {
        const u32* pp = (c >> 1) ? pw1 : pw0;
        const int a = 4 * (c & 1);
        union { u32 u[4]; bf16x8 v; } pf;
        pf.u[0] = pp[a + 0];
        pf.u[1] = pp[a + 1];
        pf.u[2] = pp[a + 2];
        pf.u[3] = pp[a + 3];
        bf16x8 vfa = va[c & 1], vfb = vb[c & 1];
        if (c < 2) {  // prefetch chunks 2,3 into the freed slots
          va[c] = *(const bf16x8*)&Vh[(size_t)c32 * 2048 + kv0 + (c + 2) * 16 + 8 * h];
          vb[c] = *(const bf16x8*)&Vh[(size_t)(32 + c32) * 2048 + kv0 + (c + 2) * 16 + 8 * h];
        }
        o0 = __builtin_amdgcn_mfma_f32_32x32x16_bf16(vfa, pf.v, o0, 0, 0, 0);
        o1 = __builtin_amdgcn_mfma_f32_32x32x16_bf16(vfb, pf.v, o1, 0, 0, 0);
      }
      __builtin_amdgcn_s_setprio(0);
    }

    // epilogue: lane owns row q=qrow; O^T reg (db,rq,jj) -> d = db*32 + 8*rq + 4*h + jj
    float inv = 1.0f / l;
    size_t yb =
        (size_t)(hd >> 4) * (2048 * 1024) + (size_t)(hd & 15) * 64 + (size_t)qrow * 1024;
#pragma unroll
    for (int db = 0; db < 2; ++db)
#pragma unroll
      for (int rq = 0; rq < 4; ++rq) {
        u16x4 pk;
#pragma unroll
        for (int jj = 0; jj < 4; ++jj)
          pk[jj] = f2bf((db ? o1[rq * 4 + jj] : o0[rq * 4 + jj]) * inv);
        *(u16x4*)&Y[yb + db * 32 + 8 * rq + 4 * h] = pk;
      }

    if (pass == 0) __syncthreads();  // Kl reuse: pass-A reads done before pass-B staging
  }
}

extern "C" void kernel_launch(void* const* d_in, const int* in_sizes, int n_in,
                              void* d_out, int out_size, void* d_ws, size_t ws_size,
                              hipStream_t stream) {
  (void)in_sizes; (void)n_in; (void)out_size; (void)ws_size;
  const float* x      = (const float*)d_in[0];
  const float* W_attn = (const float*)d_in[1];
  const float* b_attn = (const float*)d_in[2];
  const float* W_proj = (const float*)d_in[3];
  const float* b_proj = (const float*)d_in[4];
  float* out = (float*)d_out;

  char* ws = (char*)d_ws;
  u16* Xb  = (u16*)(ws);                                   // 8192*1024 bf16 (reused as Yb)
  u16* Wt  = (u16*)(ws + 16777216);                        // 3072*1024 bf16
  u16* Wpt = (u16*)(ws + 16777216 + 6291456);              // 1024*1024 bf16
  u16* QKV = (u16*)(ws + 16777216 + 6291456 + 2097152);    // 3 * 8388608 bf16
  u16* Yb  = Xb;

  conv_x_kernel<<<2048, 256, 0, stream>>>((const float4*)x, (u16x4*)Xb, 2097152);
  transpose_bf16<<<dim3(48, 16), 256, 0, stream>>>(W_attn, Wt, 1024, 3072);
  transpose_bf16<<<dim3(16, 16), 256, 0, stream>>>(W_proj, Wpt, 1024, 1024);
  gemm_bf16<0><<<1536, 256, 0, stream>>>(Xb, Wt, b_attn, nullptr, QKV, 24);
  attn_fwd<<<1024, 128, 0, stream>>>(QKV, QKV + BHTD, QKV + 2 * BHTD, Yb);
  gemm_bf16<1><<<512, 256, 0, stream>>>(Yb, Wpt, b_proj, out, nullptr, 8);
}